// Round 16
// baseline (3041.811 us; speedup 1.0000x reference)
//
#include <hip/hip_runtime.h>
#include <math.h>

#define B 128
#define T 128
#define H 128
#define RH 4
#define M 64
#define W 128
#define VOCAB 512
#define IFACE 919
#define G4 512
#define DELTA 1e-6f
#define CLIPV 20.0f

#define MEMLD 133   // mem row stride (coprime with 32)
#define LNKLD 67    // link row stride
#define CH 16       // pipeline grain: steps per chunk (W_iface amortization)
#define XILD 928    // xi row stride in LDS (16B aligned)
#define PHALF 460   // producer xi columns [0,460); consumer [460,919)
#define XSLD 464    // published xi-half row stride (16B aligned)

__device__ __forceinline__ float sigmoidf_(float x){ return 1.0f/(1.0f+expf(-x)); }
__device__ __forceinline__ float softplusf_(float x){
  return fmaxf(x, 0.0f) + log1pf(expf(-fabsf(x)));
}
__device__ __forceinline__ float waveAllSum(float v){
  for (int off=1; off<64; off<<=1) v += __shfl_xor(v, off, 64);
  return v;
}
__device__ __forceinline__ float waveAllMax(float v){
  for (int off=1; off<64; off<<=1) v = fmaxf(v, __shfl_xor(v, off, 64));
  return v;
}

__global__ void k_transpose(const float* __restrict__ in, float* __restrict__ out,
                            int rows, int cols, int use_cols){
  int idx = blockIdx.x*blockDim.x + threadIdx.x;
  int total = rows*use_cols;
  if (idx < total){
    int r = idx / use_cols, c = idx - r*use_cols;
    out[c*rows + r] = in[r*cols + c];
  }
}

// xw0[v][g] = emb[v]·w_ih0[g][0:128] + b_ih0[g] + b_hh0[g]  (coalesced via wih0T)
__global__ void k_xw0(const float* __restrict__ emb, const float* __restrict__ wih0T,
                      const float* __restrict__ b_ih0, const float* __restrict__ b_hh0,
                      float* __restrict__ xw0){
  __shared__ float e[H];
  int v = blockIdx.x, g = threadIdx.x;
  if (g < H) e[g] = emb[v*H + g];
  __syncthreads();
  float acc = b_ih0[g] + b_hh0[g];
  #pragma unroll 8
  for (int k=0;k<H;k++) acc += e[k]*wih0T[k*G4 + g];
  xw0[v*G4 + g] = acc;
}

// fused tail: per 32 (b,t) rows -> Y = stash·w_out^T + b_out -> logits -> out
__launch_bounds__(512, 1)
__global__ void k_tail(const float* __restrict__ stash, const float* __restrict__ w_out,
                       const float* __restrict__ b_out, const float* __restrict__ w_fc,
                       const float* __restrict__ b_fc, float* __restrict__ out){
  __shared__ __align__(16) float S[32*644];
  __shared__ float Y[32*129];
  const int tid = threadIdx.x;
  const long bt0 = (long)blockIdx.x*32;

  for (int idx = tid; idx < 32*640; idx += 512){
    int bt = idx / 640, k = idx - bt*640;
    S[bt*644 + k] = stash[(bt0+bt)*640 + k];
  }
  __syncthreads();
  { // Y[bt][o]
    int og = tid >> 5, bt = tid & 31;
    const float4* s4 = (const float4*)(S + bt*644);
    #pragma unroll
    for (int oo = 0; oo < 8; ++oo){
      int o = og*8 + oo;
      const float4* w4 = (const float4*)(w_out + (size_t)o*640);
      float acc = b_out[o];
      #pragma unroll 8
      for (int k4 = 0; k4 < 160; ++k4){
        float4 w = w4[k4], s = s4[k4];
        acc += w.x*s.x + w.y*s.y + w.z*s.z + w.w*s.w;
      }
      Y[bt*129 + o] = acc;
    }
  }
  __syncthreads();
  { // logits, coalesced on t
    int t = tid & 31, vg = tid >> 5;
    int b  = (int)(bt0 >> 7);
    int tb = (int)(bt0 & 127);
    const float* yr = Y + t*129;
    #pragma unroll 2
    for (int vv = 0; vv < 32; ++vv){
      int v = vg*32 + vv;
      const float4* w4 = (const float4*)(w_fc + (size_t)v*H);
      float acc = b_fc[v];
      #pragma unroll 8
      for (int k4 = 0; k4 < 32; ++k4){
        float4 w = w4[k4];
        int k = k4*4;
        acc += w.x*yr[k] + w.y*yr[k+1] + w.z*yr[k+2] + w.w*yr[k+3];
      }
      out[((size_t)b*VOCAB + v)*T + tb + t] = acc;
    }
  }
}

// Producer/consumer pipeline. Producer (blocks 0..127): LSTM scan + HALF the
// chunk xi GEMM. Consumer (blocks 128..255): computes the other xi half from
// stash-resident out rows, then the weight-free DNC memory scan.
__launch_bounds__(512, 1)
__global__ void k_dnc(const int* __restrict__ tokens,
                      const float* __restrict__ xw0,
                      const float* __restrict__ whh0T,
                      const float* __restrict__ w1catT,
                      const float* __restrict__ b_ih1,
                      const float* __restrict__ b_hh1,
                      const float* __restrict__ wifaceT,
                      const float* __restrict__ b_iface,
                      const float* __restrict__ h0,
                      float* __restrict__ xibuf,
                      float* __restrict__ stash,
                      unsigned* __restrict__ pflag,
                      unsigned* __restrict__ cflag)
{
  const int role = blockIdx.x >> 7;   // 0 = producer, 1 = consumer
  const int b = blockIdx.x & 127;
  const int tid = threadIdx.x;
  const int lane = tid & 63;
  const int wave = tid >> 6;

  __shared__ __align__(16) float hcat[2*H];
  __shared__ __align__(16) float c0s[H], c1s[H];
  __shared__ __align__(16) float mem[M*MEMLD];
  __shared__ float link[M*LNKLD];
  __shared__ float prec[M], ww[M], usage[M];
  __shared__ float rw[RH*M];
  __shared__ __align__(16) float gates[G4];
  __shared__ __align__(16) float rk[RH*W];
  __shared__ float wk[W], er[W], wv[W];
  __shared__ float memnorm[M];
  __shared__ float wcw[M], alloc_s[M];
  __shared__ float cwm[RH*M], fwd[RH*M], bwd[RH*M];
  __shared__ int   tok[T];
  __shared__ float rstr[RH], rmode[RH*3];
  __shared__ float s_wstr, s_ag, s_wg, s_wwsum, s_wkinv, s_rkinv[RH];
  __shared__ __align__(16) float xi_chunk[CH*XILD];
  __shared__ __align__(16) float out_s[CH*H];

  if (role == 0){
    // =================== PRODUCER: LSTM scan + xi half ====================
    const float b1sum = b_ih1[tid] + b_hh1[tid];
    const float bif = (tid < PHALF) ? b_iface[tid] : 0.f;

    if (tid < H){
      float hv0 = h0[0*B*H + b*H + tid];
      float hv1 = h0[1*B*H + b*H + tid];
      hcat[tid]=hv0; hcat[H+tid]=hv1; c0s[tid]=hv0; c1s[tid]=hv1;
    }
    if (tid < T) tok[tid] = tokens[b*T + tid];
    __syncthreads();

    for (int c = 0; c < T/CH; ++c){
      for (int s = 0; s < CH; ++s){
        const int t = c*CH + s;
        // mv0 (R7-proven pattern)
        {
          float acc = xw0[(size_t)tok[t]*G4 + tid];
          const float* wp = whh0T + tid;
          #pragma unroll 8
          for (int k=0;k<H;k++) acc += hcat[k]*wp[k*G4];
          gates[tid] = acc;
        }
        __syncthreads();
        if (tid < H){
          float ig = sigmoidf_(gates[tid]);
          float ff = sigmoidf_(gates[H+tid]);
          float gg = tanhf(gates[2*H+tid]);
          float og = sigmoidf_(gates[3*H+tid]);
          float c2 = ff*c0s[tid] + ig*gg;
          c0s[tid] = c2;
          hcat[tid] = og*tanhf(c2);
        }
        __syncthreads();
        // mv1 (R7-proven pattern, K=256)
        {
          float acc = b1sum;
          const float* wp1 = w1catT + tid;
          const float* wp2 = w1catT + 128*G4 + tid;
          #pragma unroll 4
          for (int k=0;k<H;k++) acc += hcat[k]*wp1[k*G4] + hcat[H+k]*wp2[k*G4];
          gates[tid] = acc;
        }
        __syncthreads();
        if (tid < H){
          float ig = sigmoidf_(gates[tid]);
          float ff = sigmoidf_(gates[H+tid]);
          float gg = tanhf(gates[2*H+tid]);
          float og = sigmoidf_(gates[3*H+tid]);
          float c2 = ff*c1s[tid] + ig*gg;
          c1s[tid] = c2;
          float h2 = og*tanhf(c2);
          hcat[H+tid] = h2;
          float ov = fminf(fmaxf(h2, -CLIPV), CLIPV);
          out_s[s*H + tid] = ov;
          stash[((long)b*T + t)*640 + tid] = ov;   // consumer reads these too
        }
        __syncthreads();
      }

      // backpressure: before overwriting slot c&1, consumer must have freed c-2
      if (c >= 2){
        if (tid == 0){
          while (__hip_atomic_load(&cflag[b], __ATOMIC_ACQUIRE,
                                   __HIP_MEMORY_SCOPE_AGENT) < (unsigned)(c-1))
            __builtin_amdgcn_s_sleep(2);
        }
        __syncthreads();
      }

      // xi GEMM, producer half: columns [0,PHALF)
      if (tid < PHALF){
        float* xslot = xibuf + ((size_t)b*2 + (c&1))*(CH*XSLD);
        float a[CH];
        #pragma unroll
        for (int r=0;r<CH;r++) a[r] = bif;
        const float* wp = wifaceT + tid;
        #pragma unroll 4
        for (int k=0;k<H;k++){
          float w1 = wp[k*IFACE];
          #pragma unroll
          for (int r=0;r<CH;r++) a[r] += out_s[r*H + k]*w1;
        }
        #pragma unroll
        for (int r=0;r<CH;r++) xslot[r*XSLD + tid] = a[r];
      }
      __syncthreads();   // all xi + stash stores issued
      if (tid == 0)
        __hip_atomic_store(&pflag[b], (unsigned)(c+1),
                           __ATOMIC_RELEASE, __HIP_MEMORY_SCOPE_AGENT);
    }
  } else {
    // =================== CONSUMER: xi half + weight-free DNC scan ==========
    const float bif2 = (tid < IFACE-PHALF) ? b_iface[PHALF+tid] : 0.f;

    for (int i = tid; i < M*MEMLD; i += 512) mem[i]=0.f;
    for (int i = tid; i < M*LNKLD; i += 512) link[i]=0.f;
    if (tid < M){ prec[tid]=0.f; ww[tid]=0.f; usage[tid]=0.f; }
    if (tid < RH*M) rw[tid]=0.f;
    __syncthreads();

    for (int c = 0; c < T/CH; ++c){
      // wait for producer chunk c (same-XCD L2 handshake)
      if (tid == 0){
        while (__hip_atomic_load(&pflag[b], __ATOMIC_ACQUIRE,
                                 __HIP_MEMORY_SCOPE_AGENT) < (unsigned)(c+1))
          __builtin_amdgcn_s_sleep(4);
      }
      __syncthreads();

      // stage out rows from stash (ordered by pflag release)
      for (int idx = tid; idx < CH*H; idx += 512){
        int r = idx >> 7, k = idx & 127;
        out_s[idx] = stash[((size_t)b*T + c*CH + r)*640 + k];
      }
      // stage producer xi half [0,PHALF) into xi_chunk
      {
        const float* src = xibuf + ((size_t)b*2 + (c&1))*(CH*XSLD);
        for (int idx = tid; idx < CH*(PHALF/4); idx += 512){
          int r = idx / (PHALF/4), q = idx - r*(PHALF/4);
          ((float4*)(xi_chunk + r*XILD))[q] = ((const float4*)(src + r*XSLD))[q];
        }
      }
      __syncthreads();
      if (tid == 0)
        __hip_atomic_store(&cflag[b], (unsigned)(c+1),
                           __ATOMIC_RELEASE, __HIP_MEMORY_SCOPE_AGENT);

      // xi GEMM, consumer half: columns [PHALF,IFACE)
      if (tid < IFACE-PHALF){
        float a[CH];
        #pragma unroll
        for (int r=0;r<CH;r++) a[r] = bif2;
        const float* wp = wifaceT + PHALF + tid;
        #pragma unroll 4
        for (int k=0;k<H;k++){
          float w1 = wp[k*IFACE];
          #pragma unroll
          for (int r=0;r<CH;r++) a[r] += out_s[r*H + k]*w1;
        }
        #pragma unroll
        for (int r=0;r<CH;r++) xi_chunk[r*XILD + PHALF + tid] = a[r];
      }
      __syncthreads();

      for (int s = 0; s < CH; ++s){
        const int t = c*CH + s;
        const long bt = (long)b*T + t;
        const float* xc = xi_chunk + s*XILD;

        // ---- parse + usage + key norms + pre-write mem-norm (merged)
        rk[tid] = tanhf(xc[tid]);
        if (tid < W){
          wk[tid] = tanhf(xc[516+tid]);
          er[tid] = sigmoidf_(xc[645+tid]);
          wv[tid] = tanhf(xc[773+tid]);
        }
        if (tid < RH){
          rstr[tid] = softplusf_(xc[512+tid]);
          float a0 = xc[907+3*tid], a1 = xc[908+3*tid], a2 = xc[909+3*tid];
          float mx = fmaxf(a0, fmaxf(a1,a2));
          float e0=expf(a0-mx), e1=expf(a1-mx), e2=expf(a2-mx);
          float s3 = e0+e1+e2;
          rmode[3*tid]=e0/s3; rmode[3*tid+1]=e1/s3; rmode[3*tid+2]=e2/s3;
        }
        if (tid == 0){
          s_wstr = softplusf_(xc[644]);
          s_ag = sigmoidf_(xc[905]);
          s_wg = sigmoidf_(xc[906]);
        }
        if (tid < M){
          float f0 = sigmoidf_(xc[901]);
          float f1 = sigmoidf_(xc[902]);
          float f2 = sigmoidf_(xc[903]);
          float f3 = sigmoidf_(xc[904]);
          float um = usage[tid] + (1.0f-usage[tid])*ww[tid];
          float psi = (1.0f - f0*rw[tid])      * (1.0f - f1*rw[M+tid])
                    * (1.0f - f2*rw[2*M+tid])  * (1.0f - f3*rw[3*M+tid]);
          usage[tid] = um*psi;
        }
        {
          int row = tid >> 3, sub = tid & 7;
          float ss = 0.f;
          #pragma unroll
          for (int i=0;i<16;i++){ float v = mem[row*MEMLD + sub + 8*i]; ss += v*v; }
          ss += __shfl_down(ss,4,8); ss += __shfl_down(ss,2,8); ss += __shfl_down(ss,1,8);
          if (sub==0) memnorm[row] = 1.0f/(sqrtf(ss)+DELTA);
        }
        if (wave == 0){
          float v0 = tanhf(xc[516+lane]), v1 = tanhf(xc[516+lane+64]);
          float ss = waveAllSum(v0*v0+v1*v1);
          if (lane==0) s_wkinv = 1.0f/(sqrtf(ss)+DELTA);
        } else if (wave <= RH){
          int r = wave-1;
          float v0 = tanhf(xc[r*W+lane]), v1 = tanhf(xc[r*W+lane+64]);
          float ss = waveAllSum(v0*v0+v1*v1);
          if (lane==0) s_rkinv[r] = 1.0f/(sqrtf(ss)+DELTA);
        }
        __syncthreads();

        // ---- Phase C: write content scores (pre-write memory)
        {
          int m = tid >> 3, sub = tid & 7;
          float d = 0.f;
          #pragma unroll
          for (int i=0;i<16;i++){ int e = sub + 8*i; d += mem[m*MEMLD + e]*wk[e]; }
          d += __shfl_down(d,4,8); d += __shfl_down(d,2,8); d += __shfl_down(d,1,8);
          if (sub==0) wcw[m] = d * memnorm[m] * s_wkinv * s_wstr;
        }
        __syncthreads();

        // ---- Phase D: wave0 softmax(wcw); wave1 allocation sort
        if (wave == 0){
          float x = wcw[lane];
          float mx = waveAllMax(x);
          float e = expf(x-mx);
          float s2 = waveAllSum(e);
          wcw[lane] = e/s2;
        } else if (wave == 1){
          float u = DELTA + (1.0f-DELTA)*usage[lane];
          int idx = lane;
          for (int k=2;k<=64;k<<=1){
            for (int j=k>>1;j>0;j>>=1){
              float ou = __shfl_xor(u, j, 64);
              int   oi = __shfl_xor(idx, j, 64);
              bool up = ((lane & k) == 0);
              bool iLower = ((lane & j) == 0);
              bool otherLess = (ou < u) || (ou == u && oi < idx);
              bool takeOther = (up == iLower) ? otherLess : !otherLess;
              if (takeOther){ u = ou; idx = oi; }
            }
          }
          float p = u;
          for (int d=1; d<64; d<<=1){
            float pv = __shfl_up(p, d, 64);
            if (lane >= d) p *= pv;
          }
          float ep = __shfl_up(p, 1, 64);
          if (lane == 0) ep = 1.0f;
          alloc_s[idx] = (1.0f - u) * ep;
        }
        __syncthreads();

        // ---- Phase F (E folded): mem write + link update, ww on the fly
        {
          const float cg = s_wg, ag = s_ag;
          #pragma unroll
          for (int e=0;e<16;e++){
            int f = tid + 512*e;
            int m = f >> 7, w = f & 127;
            float wwm = cg*(ag*alloc_s[m] + (1.0f-ag)*wcw[m]);
            mem[m*MEMLD+w] = mem[m*MEMLD+w]*(1.0f - wwm*er[w]) + wwm*wv[w];
          }
          #pragma unroll
          for (int e=0;e<8;e++){
            int f = tid + 512*e;
            int i = f >> 6, j = f & 63;
            float wwi = cg*(ag*alloc_s[i] + (1.0f-ag)*wcw[i]);
            float wwj = cg*(ag*alloc_s[j] + (1.0f-ag)*wcw[j]);
            float lv = (1.0f - wwi - wwj)*link[i*LNKLD+j] + wwi*prec[j];
            link[i*LNKLD+j] = (i==j) ? 0.0f : lv;
          }
          if (tid < M) ww[tid] = cg*(ag*alloc_s[tid] + (1.0f-ag)*wcw[tid]);
        }
        __syncthreads();

        // ---- Phase G: post-write mem norms
        {
          int row = tid >> 3, sub = tid & 7;
          float ss = 0.f;
          #pragma unroll
          for (int i=0;i<16;i++){ float v = mem[row*MEMLD + sub + 8*i]; ss += v*v; }
          ss += __shfl_down(ss,4,8); ss += __shfl_down(ss,2,8); ss += __shfl_down(ss,1,8);
          if (sub==0) memnorm[row] = 1.0f/(sqrtf(ss)+DELTA);
        }
        __syncthreads();

        // ---- Phase H+J: read dots AND fwd/bwd via link (old rw); wwsum@wave7
        {
          int r = tid >> 7, m = (tid >> 1) & 63, sub = tid & 1;
          float d = 0.f;
          #pragma unroll 8
          for (int i=0;i<64;i++){ int e = sub + 2*i; d += mem[m*MEMLD + e]*rk[r*W + e]; }
          d += __shfl_down(d,1,2);
          if (sub==0) cwm[r*M+m] = d * memnorm[m] * s_rkinv[r] * rstr[r];
        }
        if (tid < 256){
          int r = tid >> 6, i = tid & 63;
          float a = 0.f;
          #pragma unroll 8
          for (int j=0;j<M;j++) a += link[i*LNKLD+j]*rw[r*M+j];
          fwd[r*M+i] = a;
        } else {
          int q = tid - 256;
          int r = q >> 6, j = q & 63;
          float a = 0.f;
          #pragma unroll 8
          for (int i=0;i<M;i++) a += rw[r*M+i]*link[i*LNKLD+j];
          bwd[r*M+j] = a;
        }
        if (wave == 7){
          float s2 = waveAllSum(ww[lane]);
          if (lane==0) s_wwsum = s2;
        }
        __syncthreads();

        // ---- Phase I+K: per-head softmax + rw update; prec@wave4
        if (wave < RH){
          int r = wave;
          float x = cwm[r*M + lane];
          float mx = waveAllMax(x);
          float e = expf(x-mx);
          float s2 = waveAllSum(e);
          float cc = e/s2;
          rw[r*M+lane] = rmode[3*r]*bwd[r*M+lane] + rmode[3*r+1]*fwd[r*M+lane]
                       + rmode[3*r+2]*cc;
        } else if (wave == 4){
          prec[lane] = (1.0f - s_wwsum)*prec[lane] + ww[lane];
        }
        __syncthreads();

        // ---- Phase L: read vectors -> stash
        {
          int r = tid >> 7, w = tid & 127;
          float a = 0.f;
          #pragma unroll 8
          for (int m=0;m<M;m++) a += rw[r*M+m]*mem[m*MEMLD+w];
          stash[bt*640 + 128 + tid] = a;
        }
        __syncthreads();
      }
    }
  }
}

extern "C" void kernel_launch(void* const* d_in, const int* in_sizes, int n_in,
                              void* d_out, int out_size, void* d_ws, size_t ws_size,
                              hipStream_t stream)
{
  const int*   tokens  = (const int*)d_in[0];
  const float* emb     = (const float*)d_in[1];
  const float* w_ih0   = (const float*)d_in[2];
  const float* w_hh0   = (const float*)d_in[3];
  const float* b_ih0   = (const float*)d_in[4];
  const float* b_hh0   = (const float*)d_in[5];
  const float* w_ih1   = (const float*)d_in[6];
  const float* w_hh1   = (const float*)d_in[7];
  const float* b_ih1   = (const float*)d_in[8];
  const float* b_hh1   = (const float*)d_in[9];
  const float* w_iface = (const float*)d_in[10];
  const float* b_iface = (const float*)d_in[11];
  const float* w_out   = (const float*)d_in[12];
  const float* b_out   = (const float*)d_in[13];
  const float* w_fc    = (const float*)d_in[14];
  const float* b_fc    = (const float*)d_in[15];
  const float* h0      = (const float*)d_in[16];
  float* out = (float*)d_out;
  float* ws  = (float*)d_ws;

  float* xw0     = ws;                   // 262144
  float* whh0T   = xw0     + 262144;     // 65536
  float* w1catT  = whh0T   + 65536;      // 131072
  float* wifaceT = w1catT  + 131072;     // 117632
  float* wih0T   = wifaceT + 117632;     // 65536 (temp for xw0)
  float* stash   = wih0T   + 65536;      // 10485760
  float* xibuf   = stash   + 10485760;   // 128*2*(16*464) = 1900544
  unsigned* pflag = (unsigned*)(xibuf + 1900544);   // 128
  unsigned* cflag = pflag + 128;                    // 128
  // total 13,028,224 floats + 1KB = 52.11 MB (< 53.05 MB bound proven in R2)

  auto tp = [&](const float* in, float* o, int rows, int cols, int use){
    int total = rows*use;
    k_transpose<<<(total+255)/256, 256, 0, stream>>>(in, o, rows, cols, use);
  };
  tp(w_ih0,   wih0T,          512, 640, 128);
  tp(w_hh0,   whh0T,          512, 128, 128);
  tp(w_ih1,   w1catT,         512, 128, 128);
  tp(w_hh1,   w1catT+128*G4,  512, 128, 128);
  tp(w_iface, wifaceT,        919, 128, 128);
  k_xw0<<<VOCAB, 512, 0, stream>>>(emb, wih0T, b_ih0, b_hh0, xw0);
  hipMemsetAsync(pflag, 0, 256*sizeof(unsigned), stream);
  k_dnc<<<2*B, 512, 0, stream>>>(tokens, xw0, whh0T, w1catT, b_ih1, b_hh1,
                                 wifaceT, b_iface, h0, xibuf, stash,
                                 pflag, cflag);
  k_tail<<<(B*T)/32, 512, 0, stream>>>(stash, w_out, b_out, w_fc, b_fc, out);
}

// Round 17
// 2373.878 us; speedup vs baseline: 1.2814x; 1.2814x over previous
//
#include <hip/hip_runtime.h>
#include <math.h>

#define B 128
#define T 128
#define H 128
#define RH 4
#define M 64
#define W 128
#define VOCAB 512
#define IFACE 919
#define G4 512
#define DELTA 1e-6f
#define CLIPV 20.0f

#define MEMLD 133   // mem row stride; 133%32=5 coprime -> Phase H conflict-free
#define LNKLD 67    // link row stride (67%32=3, coprime)
#define CH 8        // pipeline grain: steps per chunk
#define XILD 928    // xi row stride (16B aligned)

__device__ __forceinline__ float sigmoidf_(float x){ return 1.0f/(1.0f+expf(-x)); }
__device__ __forceinline__ float softplusf_(float x){
  return fmaxf(x, 0.0f) + log1pf(expf(-fabsf(x)));
}
__device__ __forceinline__ float waveAllSum(float v){
  for (int off=1; off<64; off<<=1) v += __shfl_xor(v, off, 64);
  return v;
}
__device__ __forceinline__ float waveAllMax(float v){
  for (int off=1; off<64; off<<=1) v = fmaxf(v, __shfl_xor(v, off, 64));
  return v;
}

__global__ void k_transpose(const float* __restrict__ in, float* __restrict__ out,
                            int rows, int cols, int use_cols){
  int idx = blockIdx.x*blockDim.x + threadIdx.x;
  int total = rows*use_cols;
  if (idx < total){
    int r = idx / use_cols, c = idx - r*use_cols;
    out[c*rows + r] = in[r*cols + c];
  }
}

// xw0[v][g] = emb[v]·w_ih0[g][0:128] + b_ih0[g] + b_hh0[g]  (coalesced via wih0T)
__global__ void k_xw0(const float* __restrict__ emb, const float* __restrict__ wih0T,
                      const float* __restrict__ b_ih0, const float* __restrict__ b_hh0,
                      float* __restrict__ xw0){
  __shared__ float e[H];
  int v = blockIdx.x, g = threadIdx.x;
  if (g < H) e[g] = emb[v*H + g];
  __syncthreads();
  float acc = b_ih0[g] + b_hh0[g];
  #pragma unroll 8
  for (int k=0;k<H;k++) acc += e[k]*wih0T[k*G4 + g];
  xw0[v*G4 + g] = acc;
}

// fused tail: per 32 (b,t) rows -> Y = stash·w_out^T + b_out -> logits -> out
__launch_bounds__(512, 1)
__global__ void k_tail(const float* __restrict__ stash, const float* __restrict__ w_out,
                       const float* __restrict__ b_out, const float* __restrict__ w_fc,
                       const float* __restrict__ b_fc, float* __restrict__ out){
  __shared__ __align__(16) float S[32*644];
  __shared__ float Y[32*129];
  const int tid = threadIdx.x;
  const long bt0 = (long)blockIdx.x*32;

  for (int idx = tid; idx < 32*640; idx += 512){
    int bt = idx / 640, k = idx - bt*640;
    S[bt*644 + k] = stash[(bt0+bt)*640 + k];
  }
  __syncthreads();
  { // Y[bt][o]
    int og = tid >> 5, bt = tid & 31;
    const float4* s4 = (const float4*)(S + bt*644);
    #pragma unroll
    for (int oo = 0; oo < 8; ++oo){
      int o = og*8 + oo;
      const float4* w4 = (const float4*)(w_out + (size_t)o*640);
      float acc = b_out[o];
      #pragma unroll 8
      for (int k4 = 0; k4 < 160; ++k4){
        float4 w = w4[k4], s = s4[k4];
        acc += w.x*s.x + w.y*s.y + w.z*s.z + w.w*s.w;
      }
      Y[bt*129 + o] = acc;
    }
  }
  __syncthreads();
  { // logits, coalesced on t
    int t = tid & 31, vg = tid >> 5;
    int b  = (int)(bt0 >> 7);
    int tb = (int)(bt0 & 127);
    const float* yr = Y + t*129;
    #pragma unroll 2
    for (int vv = 0; vv < 32; ++vv){
      int v = vg*32 + vv;
      const float4* w4 = (const float4*)(w_fc + (size_t)v*H);
      float acc = b_fc[v];
      #pragma unroll 8
      for (int k4 = 0; k4 < 32; ++k4){
        float4 w = w4[k4];
        int k = k4*4;
        acc += w.x*yr[k] + w.y*yr[k+1] + w.z*yr[k+2] + w.w*yr[k+3];
      }
      out[((size_t)b*VOCAB + v)*T + tb + t] = acc;
    }
  }
}

// Producer/consumer pipeline. Producer (blocks 0..127): LSTM scan + per-chunk
// xi GEMM (fills its L2-stall windows), publishes xi into a 2-slot ring.
// Consumer (blocks 128..255): weight-free DNC memory scan from staged xi.
__launch_bounds__(512, 1)
__global__ void k_dnc(const int* __restrict__ tokens,
                      const float* __restrict__ xw0,
                      const float* __restrict__ whh0T,
                      const float* __restrict__ w1catT,
                      const float* __restrict__ b_ih1,
                      const float* __restrict__ b_hh1,
                      const float* __restrict__ wifaceT,
                      const float* __restrict__ b_iface,
                      const float* __restrict__ h0,
                      float* __restrict__ xibuf,
                      float* __restrict__ stash,
                      unsigned* __restrict__ pflag,
                      unsigned* __restrict__ cflag)
{
  const int role = blockIdx.x >> 7;   // 0 = producer (LSTM+xi), 1 = consumer (DNC)
  const int b = blockIdx.x & 127;
  const int tid = threadIdx.x;
  const int lane = tid & 63;
  const int wave = tid >> 6;

  __shared__ __align__(16) float hcat[2*H];
  __shared__ __align__(16) float c0s[H], c1s[H];
  __shared__ __align__(16) float mem[M*MEMLD];
  __shared__ float link[M*LNKLD];
  __shared__ float prec[M], ww[M], usage[M];
  __shared__ float rw[RH*M];
  __shared__ __align__(16) float gates[G4];
  __shared__ __align__(16) float rk[RH*W];
  __shared__ float wk[W], er[W], wv[W];
  __shared__ float memnorm[M];
  __shared__ float wcw[M], alloc_s[M];
  __shared__ float cwm[RH*M], fwd[RH*M], bwd[RH*M];
  __shared__ int   tok[T];
  __shared__ float rstr[RH], rmode[RH*3];
  __shared__ float s_wstr, s_ag, s_wg, s_wwsum, s_wkinv, s_rkinv[RH];
  __shared__ __align__(16) float xi_chunk[CH*XILD];
  __shared__ __align__(16) float out_s[CH*H];

  if (role == 0){
    // =================== PRODUCER: LSTM scan + chunk xi GEMM ================
    const float b1sum = b_ih1[tid] + b_hh1[tid];
    const bool  two = (tid < IFACE-512);
    const float bi0 = b_iface[tid];
    const float bi1 = two ? b_iface[tid+512] : 0.f;

    if (tid < H){
      float hv0 = h0[0*B*H + b*H + tid];
      float hv1 = h0[1*B*H + b*H + tid];
      hcat[tid]=hv0; hcat[H+tid]=hv1; c0s[tid]=hv0; c1s[tid]=hv1;
    }
    if (tid < T) tok[tid] = tokens[b*T + tid];
    __syncthreads();

    for (int c = 0; c < T/CH; ++c){
      for (int s = 0; s < CH; ++s){
        const int t = c*CH + s;
        // mv0 (R7-proven pattern)
        {
          float acc = xw0[(size_t)tok[t]*G4 + tid];
          const float* wp = whh0T + tid;
          #pragma unroll 8
          for (int k=0;k<H;k++) acc += hcat[k]*wp[k*G4];
          gates[tid] = acc;
        }
        __syncthreads();
        if (tid < H){
          float ig = sigmoidf_(gates[tid]);
          float ff = sigmoidf_(gates[H+tid]);
          float gg = tanhf(gates[2*H+tid]);
          float og = sigmoidf_(gates[3*H+tid]);
          float c2 = ff*c0s[tid] + ig*gg;
          c0s[tid] = c2;
          hcat[tid] = og*tanhf(c2);
        }
        __syncthreads();
        // mv1 (R7-proven pattern, K=256)
        {
          float acc = b1sum;
          const float* wp1 = w1catT + tid;
          const float* wp2 = w1catT + 128*G4 + tid;
          #pragma unroll 4
          for (int k=0;k<H;k++) acc += hcat[k]*wp1[k*G4] + hcat[H+k]*wp2[k*G4];
          gates[tid] = acc;
        }
        __syncthreads();
        if (tid < H){
          float ig = sigmoidf_(gates[tid]);
          float ff = sigmoidf_(gates[H+tid]);
          float gg = tanhf(gates[2*H+tid]);
          float og = sigmoidf_(gates[3*H+tid]);
          float c2 = ff*c1s[tid] + ig*gg;
          c1s[tid] = c2;
          float h2 = og*tanhf(c2);
          hcat[H+tid] = h2;
          float ov = fminf(fmaxf(h2, -CLIPV), CLIPV);
          out_s[s*H + tid] = ov;               // for this chunk's xi GEMM
          stash[((long)b*T + t)*640 + tid] = ov;
        }
        __syncthreads();
      }

      // backpressure: before overwriting slot c&1, consumer must have staged c-2
      if (c >= 2){
        if (tid == 0){
          while (__hip_atomic_load(&cflag[b], __ATOMIC_ACQUIRE,
                                   __HIP_MEMORY_SCOPE_AGENT) < (unsigned)(c-1))
            __builtin_amdgcn_s_sleep(2);
        }
        __syncthreads();
      }

      // xi GEMM for this chunk (W_iface streamed once per CH steps)
      {
        float* xslot = xibuf + ((size_t)b*2 + (c&1))*(CH*XILD);
        float a0[CH], a1[CH];
        #pragma unroll
        for (int r=0;r<CH;r++){ a0[r] = bi0; a1[r] = bi1; }
        const float* wp1 = wifaceT + tid;
        const float* wp2 = wifaceT + tid + 512;
        #pragma unroll 4
        for (int k=0;k<H;k++){
          float w1 = wp1[k*IFACE];
          float w2 = two ? wp2[k*IFACE] : 0.f;
          #pragma unroll
          for (int r=0;r<CH;r++){
            float o = out_s[r*H + k];
            a0[r] += o*w1;
            a1[r] += o*w2;
          }
        }
        #pragma unroll
        for (int r=0;r<CH;r++){
          xslot[r*XILD + tid] = a0[r];
          if (two) xslot[r*XILD + tid + 512] = a1[r];
        }
      }
      __syncthreads();   // all xi stores issued
      if (tid == 0)
        __hip_atomic_store(&pflag[b], (unsigned)(c+1),
                           __ATOMIC_RELEASE, __HIP_MEMORY_SCOPE_AGENT);
    }
  } else {
    // =================== CONSUMER: weight-free DNC scan =====================
    for (int i = tid; i < M*MEMLD; i += 512) mem[i]=0.f;
    for (int i = tid; i < M*LNKLD; i += 512) link[i]=0.f;
    if (tid < M){ prec[tid]=0.f; ww[tid]=0.f; usage[tid]=0.f; }
    if (tid < RH*M) rw[tid]=0.f;
    __syncthreads();

    for (int c = 0; c < T/CH; ++c){
      // wait for producer chunk c (same-XCD L2 handshake)
      if (tid == 0){
        while (__hip_atomic_load(&pflag[b], __ATOMIC_ACQUIRE,
                                 __HIP_MEMORY_SCOPE_AGENT) < (unsigned)(c+1))
          __builtin_amdgcn_s_sleep(4);
      }
      __syncthreads();

      // stage xi chunk (30KB, float4-coalesced), then free the slot
      {
        const float4* src = (const float4*)(xibuf + ((size_t)b*2 + (c&1))*(CH*XILD));
        float4* dst = (float4*)xi_chunk;
        for (int i = tid; i < CH*XILD/4; i += 512) dst[i] = src[i];
      }
      __syncthreads();
      if (tid == 0)
        __hip_atomic_store(&cflag[b], (unsigned)(c+1),
                           __ATOMIC_RELEASE, __HIP_MEMORY_SCOPE_AGENT);

      for (int s = 0; s < CH; ++s){
        const int t = c*CH + s;
        const long bt = (long)b*T + t;
        const float* xc = xi_chunk + s*XILD;

        // ---- parse + usage + key norms + pre-write mem-norm (merged)
        rk[tid] = tanhf(xc[tid]);
        if (tid < W){
          wk[tid] = tanhf(xc[516+tid]);
          er[tid] = sigmoidf_(xc[645+tid]);
          wv[tid] = tanhf(xc[773+tid]);
        }
        if (tid < RH){
          rstr[tid] = softplusf_(xc[512+tid]);
          float a0 = xc[907+3*tid], a1 = xc[908+3*tid], a2 = xc[909+3*tid];
          float mx = fmaxf(a0, fmaxf(a1,a2));
          float e0=expf(a0-mx), e1=expf(a1-mx), e2=expf(a2-mx);
          float s3 = e0+e1+e2;
          rmode[3*tid]=e0/s3; rmode[3*tid+1]=e1/s3; rmode[3*tid+2]=e2/s3;
        }
        if (tid == 0){
          s_wstr = softplusf_(xc[644]);
          s_ag = sigmoidf_(xc[905]);
          s_wg = sigmoidf_(xc[906]);
        }
        if (tid < M){
          float f0 = sigmoidf_(xc[901]);
          float f1 = sigmoidf_(xc[902]);
          float f2 = sigmoidf_(xc[903]);
          float f3 = sigmoidf_(xc[904]);
          float um = usage[tid] + (1.0f-usage[tid])*ww[tid];
          float psi = (1.0f - f0*rw[tid])      * (1.0f - f1*rw[M+tid])
                    * (1.0f - f2*rw[2*M+tid])  * (1.0f - f3*rw[3*M+tid]);
          usage[tid] = um*psi;
        }
        {
          int row = tid >> 3, sub = tid & 7;
          float ss = 0.f;
          #pragma unroll
          for (int i=0;i<16;i++){ float v = mem[row*MEMLD + sub + 8*i]; ss += v*v; }
          ss += __shfl_down(ss,4,8); ss += __shfl_down(ss,2,8); ss += __shfl_down(ss,1,8);
          if (sub==0) memnorm[row] = 1.0f/(sqrtf(ss)+DELTA);
        }
        if (wave == 0){
          float v0 = tanhf(xc[516+lane]), v1 = tanhf(xc[516+lane+64]);
          float ss = waveAllSum(v0*v0+v1*v1);
          if (lane==0) s_wkinv = 1.0f/(sqrtf(ss)+DELTA);
        } else if (wave <= RH){
          int r = wave-1;
          float v0 = tanhf(xc[r*W+lane]), v1 = tanhf(xc[r*W+lane+64]);
          float ss = waveAllSum(v0*v0+v1*v1);
          if (lane==0) s_rkinv[r] = 1.0f/(sqrtf(ss)+DELTA);
        }
        __syncthreads();

        // ---- Phase C: write content scores (pre-write memory)
        {
          int m = tid >> 3, sub = tid & 7;
          float d = 0.f;
          #pragma unroll
          for (int i=0;i<16;i++){ int e = sub + 8*i; d += mem[m*MEMLD + e]*wk[e]; }
          d += __shfl_down(d,4,8); d += __shfl_down(d,2,8); d += __shfl_down(d,1,8);
          if (sub==0) wcw[m] = d * memnorm[m] * s_wkinv * s_wstr;
        }
        __syncthreads();

        // ---- Phase D: wave0 softmax(wcw); wave1 allocation sort
        if (wave == 0){
          float x = wcw[lane];
          float mx = waveAllMax(x);
          float e = expf(x-mx);
          float s2 = waveAllSum(e);
          wcw[lane] = e/s2;
        } else if (wave == 1){
          float u = DELTA + (1.0f-DELTA)*usage[lane];
          int idx = lane;
          for (int k=2;k<=64;k<<=1){
            for (int j=k>>1;j>0;j>>=1){
              float ou = __shfl_xor(u, j, 64);
              int   oi = __shfl_xor(idx, j, 64);
              bool up = ((lane & k) == 0);
              bool iLower = ((lane & j) == 0);
              bool otherLess = (ou < u) || (ou == u && oi < idx);
              bool takeOther = (up == iLower) ? otherLess : !otherLess;
              if (takeOther){ u = ou; idx = oi; }
            }
          }
          float p = u;
          for (int d=1; d<64; d<<=1){
            float pv = __shfl_up(p, d, 64);
            if (lane >= d) p *= pv;
          }
          float ep = __shfl_up(p, 1, 64);
          if (lane == 0) ep = 1.0f;
          alloc_s[idx] = (1.0f - u) * ep;
        }
        __syncthreads();

        // ---- Phase F (E folded): mem write + link update, ww on the fly
        {
          const float cg = s_wg, ag = s_ag;
          #pragma unroll
          for (int e=0;e<16;e++){
            int f = tid + 512*e;
            int m = f >> 7, w = f & 127;
            float wwm = cg*(ag*alloc_s[m] + (1.0f-ag)*wcw[m]);
            mem[m*MEMLD+w] = mem[m*MEMLD+w]*(1.0f - wwm*er[w]) + wwm*wv[w];
          }
          #pragma unroll
          for (int e=0;e<8;e++){
            int f = tid + 512*e;
            int i = f >> 6, j = f & 63;
            float wwi = cg*(ag*alloc_s[i] + (1.0f-ag)*wcw[i]);
            float wwj = cg*(ag*alloc_s[j] + (1.0f-ag)*wcw[j]);
            float lv = (1.0f - wwi - wwj)*link[i*LNKLD+j] + wwi*prec[j];
            link[i*LNKLD+j] = (i==j) ? 0.0f : lv;
          }
          if (tid < M) ww[tid] = cg*(ag*alloc_s[tid] + (1.0f-ag)*wcw[tid]);
        }
        __syncthreads();

        // ---- Phase G: post-write mem norms
        {
          int row = tid >> 3, sub = tid & 7;
          float ss = 0.f;
          #pragma unroll
          for (int i=0;i<16;i++){ float v = mem[row*MEMLD + sub + 8*i]; ss += v*v; }
          ss += __shfl_down(ss,4,8); ss += __shfl_down(ss,2,8); ss += __shfl_down(ss,1,8);
          if (sub==0) memnorm[row] = 1.0f/(sqrtf(ss)+DELTA);
        }
        __syncthreads();

        // ---- Phase H+J: read dots AND fwd/bwd via link (old rw); wwsum@wave7
        {
          int r = tid >> 7, m = (tid >> 1) & 63, sub = tid & 1;
          float d = 0.f;
          #pragma unroll 8
          for (int i=0;i<64;i++){ int e = sub + 2*i; d += mem[m*MEMLD + e]*rk[r*W + e]; }
          d += __shfl_down(d,1,2);
          if (sub==0) cwm[r*M+m] = d * memnorm[m] * s_rkinv[r] * rstr[r];
        }
        if (tid < 256){
          int r = tid >> 6, i = tid & 63;
          float a = 0.f;
          #pragma unroll 8
          for (int j=0;j<M;j++) a += link[i*LNKLD+j]*rw[r*M+j];
          fwd[r*M+i] = a;
        } else {
          int q = tid - 256;
          int r = q >> 6, j = q & 63;
          float a = 0.f;
          #pragma unroll 8
          for (int i=0;i<M;i++) a += rw[r*M+i]*link[i*LNKLD+j];
          bwd[r*M+j] = a;
        }
        if (wave == 7){
          float s2 = waveAllSum(ww[lane]);
          if (lane==0) s_wwsum = s2;
        }
        __syncthreads();

        // ---- Phase I+K: per-head softmax + rw update; prec@wave4
        if (wave < RH){
          int r = wave;
          float x = cwm[r*M + lane];
          float mx = waveAllMax(x);
          float e = expf(x-mx);
          float s2 = waveAllSum(e);
          float cc = e/s2;
          rw[r*M+lane] = rmode[3*r]*bwd[r*M+lane] + rmode[3*r+1]*fwd[r*M+lane]
                       + rmode[3*r+2]*cc;
        } else if (wave == 4){
          prec[lane] = (1.0f - s_wwsum)*prec[lane] + ww[lane];
        }
        __syncthreads();

        // ---- Phase L: read vectors -> stash
        {
          int r = tid >> 7, w = tid & 127;
          float a = 0.f;
          #pragma unroll 8
          for (int m=0;m<M;m++) a += rw[r*M+m]*mem[m*MEMLD+w];
          stash[bt*640 + 128 + tid] = a;
        }
        __syncthreads();
      }
    }
  }
}

extern "C" void kernel_launch(void* const* d_in, const int* in_sizes, int n_in,
                              void* d_out, int out_size, void* d_ws, size_t ws_size,
                              hipStream_t stream)
{
  const int*   tokens  = (const int*)d_in[0];
  const float* emb     = (const float*)d_in[1];
  const float* w_ih0   = (const float*)d_in[2];
  const float* w_hh0   = (const float*)d_in[3];
  const float* b_ih0   = (const float*)d_in[4];
  const float* b_hh0   = (const float*)d_in[5];
  const float* w_ih1   = (const float*)d_in[6];
  const float* w_hh1   = (const float*)d_in[7];
  const float* b_ih1   = (const float*)d_in[8];
  const float* b_hh1   = (const float*)d_in[9];
  const float* w_iface = (const float*)d_in[10];
  const float* b_iface = (const float*)d_in[11];
  const float* w_out   = (const float*)d_in[12];
  const float* b_out   = (const float*)d_in[13];
  const float* w_fc    = (const float*)d_in[14];
  const float* b_fc    = (const float*)d_in[15];
  const float* h0      = (const float*)d_in[16];
  float* out = (float*)d_out;
  float* ws  = (float*)d_ws;

  float* xw0     = ws;                   // 262144
  float* whh0T   = xw0     + 262144;     // 65536
  float* w1catT  = whh0T   + 65536;      // 131072
  float* wifaceT = w1catT  + 131072;     // 117632
  float* wih0T   = wifaceT + 117632;     // 65536 (temp for xw0)
  float* stash   = wih0T   + 65536;      // 10485760
  float* xibuf   = stash   + 10485760;   // 128*2*7424 = 1900544
  unsigned* pflag = (unsigned*)(xibuf + 1900544);   // 128
  unsigned* cflag = pflag + 128;                    // 128
  // total 13,028,224 floats + 1KB = 52.11 MB (< 53.05 MB bound proven in R2)

  auto tp = [&](const float* in, float* o, int rows, int cols, int use){
    int total = rows*use;
    k_transpose<<<(total+255)/256, 256, 0, stream>>>(in, o, rows, cols, use);
  };
  tp(w_ih0,   wih0T,          512, 640, 128);
  tp(w_hh0,   whh0T,          512, 128, 128);
  tp(w_ih1,   w1catT,         512, 128, 128);
  tp(w_hh1,   w1catT+128*G4,  512, 128, 128);
  tp(w_iface, wifaceT,        919, 128, 128);
  k_xw0<<<VOCAB, 512, 0, stream>>>(emb, wih0T, b_ih0, b_hh0, xw0);
  hipMemsetAsync(pflag, 0, 256*sizeof(unsigned), stream);
  k_dnc<<<2*B, 512, 0, stream>>>(tokens, xw0, whh0T, w1catT, b_ih1, b_hh1,
                                 wifaceT, b_iface, h0, xibuf, stash,
                                 pflag, cflag);
  k_tail<<<(B*T)/32, 512, 0, stream>>>(stash, w_out, b_out, w_fc, b_fc, out);
}